// Round 1
// baseline (96.224 us; speedup 1.0000x reference)
//
#include <hip/hip_runtime.h>

typedef unsigned short ushort_t;
typedef unsigned int uint32;

typedef __bf16 bf16x8 __attribute__((ext_vector_type(8)));
typedef float f32x4 __attribute__((ext_vector_type(4)));

// ---------- helpers ----------
__device__ __forceinline__ uint32 f2bf1(float f) {
  uint32 b = __float_as_uint(f);
  return (b + 0x7FFFu + ((b >> 16) & 1u)) >> 16;  // RNE
}
__device__ __forceinline__ uint32 packbf2(float a, float b) {
  return f2bf1(a) | (f2bf1(b) << 16);
}
__device__ __forceinline__ float bflo(uint32 u) { return __uint_as_float(u << 16); }
__device__ __forceinline__ float bfhi(uint32 u) { return __uint_as_float(u & 0xFFFF0000u); }

__device__ __forceinline__ void gload16(const void* g, void* l) {
  __builtin_amdgcn_global_load_lds(
      (const __attribute__((address_space(1))) unsigned int*)g,
      (__attribute__((address_space(3))) unsigned int*)l, 16, 0, 0);
}

// ---------- fp32 -> bf16 elementwise convert ----------
__global__ __launch_bounds__(256) void cvt_f32_bf16(
    const float* __restrict__ in, ushort_t* __restrict__ out, int n4) {
  int i = blockIdx.x * 256 + threadIdx.x;
  if (i < n4) {
    float4 v = ((const float4*)in)[i];
    uint2 r;
    r.x = packbf2(v.x, v.y);
    r.y = packbf2(v.z, v.w);
    ((uint2*)out)[i] = r;
  }
}

// ---------- fp32 [R][Cc] -> bf16 [Cc][R] (transpose + convert) ----------
__global__ __launch_bounds__(256) void transpose_cvt(
    const float* __restrict__ Wsrc, ushort_t* __restrict__ Wt, int R, int Cc) {
  __shared__ float tile[32][33];
  const int tx = threadIdx.x & 31, ty = threadIdx.x >> 5;
  const int c0 = blockIdx.x << 5, r0 = blockIdx.y << 5;
#pragma unroll
  for (int i = 0; i < 4; ++i)
    tile[ty + i * 8][tx] = Wsrc[(size_t)(r0 + ty + i * 8) * Cc + c0 + tx];
  __syncthreads();
#pragma unroll
  for (int i = 0; i < 4; ++i)
    Wt[(size_t)(c0 + ty + i * 8) * R + r0 + tx] = (ushort_t)f2bf1(tile[tx][ty + i * 8]);
}

// ---------- bf16 GEMM: C[M][Nn] = A[M][K] * Bt[Nn][K]^T (+bias) ----------
// m97 structure: 128x128 tile, BK=32, 4 waves (2x2), 64x64 per wave,
// global_load_lds width=16, 2-barrier K loop.
template <bool OUT_BF16>
__global__ __launch_bounds__(256) void gemm_bt(
    const ushort_t* __restrict__ A, const ushort_t* __restrict__ Bt,
    void* __restrict__ Cout, const float* __restrict__ bias,
    const int M, const int Nn, const int K) {
  __shared__ ushort_t lA[128 * 32];
  __shared__ ushort_t lB[128 * 32];
  const int tid = threadIdx.x;
  const int lane = tid & 63, wave = tid >> 6;
  const int wm = wave >> 1, wn = wave & 1;
  const int bm = blockIdx.y << 7, bn = blockIdx.x << 7;

  f32x4 acc[4][4] = {};

  // staging: thread t covers row t>>2 (rounds of 64 rows), 16B chunk t&3
  const int srow = tid >> 2, schk = tid & 3;
  const ushort_t* gA = A + (size_t)(bm + srow) * K + schk * 8;
  const ushort_t* gB = Bt + (size_t)(bn + srow) * K + schk * 8;
  ushort_t* lA0 = lA + wave * 512;  // wave-uniform LDS base (1KB per wave)
  ushort_t* lB0 = lB + wave * 512;

  const int la_off = ((wm << 6) + (lane & 15)) * 32 + ((lane >> 4) << 3);
  const int lb_off = ((wn << 6) + (lane & 15)) * 32 + ((lane >> 4) << 3);

  for (int k0 = 0; k0 < K; k0 += 32) {
    gload16(gA + k0, lA0);
    gload16(gA + k0 + 64 * K, lA0 + 2048);
    gload16(gB + k0, lB0);
    gload16(gB + k0 + 64 * K, lB0 + 2048);
    __syncthreads();  // compiler drains vmcnt before barrier
    bf16x8 a[4], b[4];
#pragma unroll
    for (int m = 0; m < 4; ++m) a[m] = *(const bf16x8*)&lA[la_off + m * 512];
#pragma unroll
    for (int n = 0; n < 4; ++n) b[n] = *(const bf16x8*)&lB[lb_off + n * 512];
#pragma unroll
    for (int m = 0; m < 4; ++m)
#pragma unroll
      for (int n = 0; n < 4; ++n)
        acc[m][n] = __builtin_amdgcn_mfma_f32_16x16x32_bf16(a[m], b[n], acc[m][n], 0, 0, 0);
    __syncthreads();
  }

  // epilogue: C/D layout col=lane&15, row=(lane>>4)*4+reg  [m89/m91 verified]
  const int r0 = bm + (wm << 6) + ((lane >> 4) << 2);
  const int c0 = bn + (wn << 6) + (lane & 15);
#pragma unroll
  for (int m = 0; m < 4; ++m)
#pragma unroll
    for (int n = 0; n < 4; ++n)
#pragma unroll
      for (int j = 0; j < 4; ++j) {
        const int row = r0 + m * 16 + j;
        const int col = c0 + n * 16;
        if (OUT_BF16)
          ((ushort_t*)Cout)[(size_t)row * Nn + col] = (ushort_t)f2bf1(acc[m][n][j]);
        else
          ((float*)Cout)[(size_t)row * Nn + col] = acc[m][n][j] + bias[col];
      }
}

// ---------- banded attention ----------
// qkv: [B*N][3072] bf16, cols = s*1024 + h*64 + d.  aout: [B*N][1024] bf16.
// Block = (b, h, 64-query tile). LDS: K/V rows i0-8..i0+71 as fp32, stride 68.
// Wave: 16 queries; lane = (qs = lane>>2, dg = lane&3) -> query, 16-dim quarter.
__global__ __launch_bounds__(256) void attn_band(
    const ushort_t* __restrict__ qkv, ushort_t* __restrict__ aout) {
  __shared__ float Ks[80 * 68];
  __shared__ float Vs[80 * 68];
  const int tid = threadIdx.x;
  const int i0 = blockIdx.x << 6;
  const int h = blockIdx.y;
  const int b = blockIdx.z;
  const size_t rowbase = (size_t)b * 2048;

  // stage K and V (zero-fill out-of-range rows)
  for (int idx = tid; idx < 1280; idx += 256) {
    const int t = idx >> 4, c = idx & 15;
    const int j = i0 - 8 + t;
    float k0 = 0.f, k1 = 0.f, k2 = 0.f, k3 = 0.f;
    float v0 = 0.f, v1 = 0.f, v2 = 0.f, v3 = 0.f;
    if ((unsigned)j < 2048u) {
      const ushort_t* p = qkv + (rowbase + j) * 3072 + (h << 6) + (c << 2);
      uint2 rk = *(const uint2*)(p + 1024);
      uint2 rv = *(const uint2*)(p + 2048);
      k0 = bflo(rk.x); k1 = bfhi(rk.x); k2 = bflo(rk.y); k3 = bfhi(rk.y);
      v0 = bflo(rv.x); v1 = bfhi(rv.x); v2 = bflo(rv.y); v3 = bfhi(rv.y);
    }
    *(float4*)&Ks[t * 68 + (c << 2)] = make_float4(k0, k1, k2, k3);
    *(float4*)&Vs[t * 68 + (c << 2)] = make_float4(v0, v1, v2, v3);
  }
  __syncthreads();

  const int lane = tid & 63, wv = tid >> 6;
  const int qs = lane >> 2, dg = lane & 3;
  const int qi = (wv << 4) + qs;  // local query 0..63
  const int i = i0 + qi;          // global query

  // load q (16 fp32 from bf16)
  const ushort_t* qp = qkv + (rowbase + i) * 3072 + (h << 6) + (dg << 4);
  float q[16];
  {
    uint4 u0 = *(const uint4*)qp;
    uint4 u1 = *(const uint4*)(qp + 8);
    q[0] = bflo(u0.x); q[1] = bfhi(u0.x); q[2] = bflo(u0.y); q[3] = bfhi(u0.y);
    q[4] = bflo(u0.z); q[5] = bfhi(u0.z); q[6] = bflo(u0.w); q[7] = bfhi(u0.w);
    q[8] = bflo(u1.x); q[9] = bfhi(u1.x); q[10] = bflo(u1.y); q[11] = bfhi(u1.y);
    q[12] = bflo(u1.z); q[13] = bfhi(u1.z); q[14] = bflo(u1.w); q[15] = bfhi(u1.w);
  }

  float s[17];
#pragma unroll
  for (int jo = 0; jo < 17; ++jo) {
    const float* kr = &Ks[(qi + jo) * 68 + (dg << 4)];
    float d = 0.f;
#pragma unroll
    for (int c = 0; c < 4; ++c) {
      float4 kv = *(const float4*)(kr + (c << 2));
      d += q[c * 4 + 0] * kv.x + q[c * 4 + 1] * kv.y +
           q[c * 4 + 2] * kv.z + q[c * 4 + 3] * kv.w;
    }
    d += __shfl_xor(d, 1);  // reduce across the 4 dg lanes (DPP quad)
    d += __shfl_xor(d, 2);
    const int jg = i - 8 + jo;
    s[jo] = ((unsigned)jg < 2048u) ? d * 0.125f : -1e30f;
  }
  float m = s[0];
#pragma unroll
  for (int jo = 1; jo < 17; ++jo) m = fmaxf(m, s[jo]);
  float sum = 0.f;
#pragma unroll
  for (int jo = 0; jo < 17; ++jo) {
    s[jo] = __expf(s[jo] - m);
    sum += s[jo];
  }
  const float inv = 1.f / sum;

  float o[16];
#pragma unroll
  for (int dd = 0; dd < 16; ++dd) o[dd] = 0.f;
#pragma unroll
  for (int jo = 0; jo < 17; ++jo) {
    const float* vr = &Vs[(qi + jo) * 68 + (dg << 4)];
    const float w = s[jo];
#pragma unroll
    for (int c = 0; c < 4; ++c) {
      float4 vv = *(const float4*)(vr + (c << 2));
      o[c * 4 + 0] += w * vv.x; o[c * 4 + 1] += w * vv.y;
      o[c * 4 + 2] += w * vv.z; o[c * 4 + 3] += w * vv.w;
    }
  }

  ushort_t* op = aout + (rowbase + i) * 1024 + (h << 6) + (dg << 4);
  uint4 w0, w1;
  w0.x = packbf2(o[0] * inv, o[1] * inv);
  w0.y = packbf2(o[2] * inv, o[3] * inv);
  w0.z = packbf2(o[4] * inv, o[5] * inv);
  w0.w = packbf2(o[6] * inv, o[7] * inv);
  w1.x = packbf2(o[8] * inv, o[9] * inv);
  w1.y = packbf2(o[10] * inv, o[11] * inv);
  w1.z = packbf2(o[12] * inv, o[13] * inv);
  w1.w = packbf2(o[14] * inv, o[15] * inv);
  *(uint4*)op = w0;
  *(uint4*)(op + 8) = w1;
}

// ---------- launch ----------
extern "C" void kernel_launch(void* const* d_in, const int* in_sizes, int n_in,
                              void* d_out, int out_size, void* d_ws, size_t ws_size,
                              hipStream_t stream) {
  const float* x = (const float*)d_in[0];       // [2,2048,1024]
  const float* Wqkv = (const float*)d_in[1];    // [1024,3072]
  const float* Wproj = (const float*)d_in[2];   // [1024,1024]
  const float* bproj = (const float*)d_in[3];   // [1024]
  float* out = (float*)d_out;                   // [2,2048,1024] fp32

  char* ws = (char*)d_ws;
  ushort_t* xb    = (ushort_t*)(ws);                   // 8 MB: x bf16 [4096][1024]
  ushort_t* wqkvT = (ushort_t*)(ws + (8u << 20));      // 6 MB: WqkvT bf16 [3072][1024]
  ushort_t* wprT  = (ushort_t*)(ws + (14u << 20));     // 2 MB: WprojT bf16 [1024][1024]
  ushort_t* qkv   = (ushort_t*)(ws + (16u << 20));     // 24 MB: qkv bf16 [4096][3072]
  ushort_t* aoutb = (ushort_t*)(ws + (40u << 20));     // 8 MB: attn out bf16 [4096][1024]

  cvt_f32_bf16<<<4096, 256, 0, stream>>>(x, xb, 1048576);
  transpose_cvt<<<dim3(96, 32), 256, 0, stream>>>(Wqkv, wqkvT, 1024, 3072);
  transpose_cvt<<<dim3(32, 32), 256, 0, stream>>>(Wproj, wprT, 1024, 1024);
  gemm_bt<true><<<dim3(24, 32), 256, 0, stream>>>(xb, wqkvT, qkv, nullptr, 4096, 3072, 1024);
  attn_band<<<dim3(32, 16, 2), 256, 0, stream>>>(qkv, aoutb);
  gemm_bt<false><<<dim3(8, 32), 256, 0, stream>>>(aoutb, wprT, out, bproj, 4096, 1024, 1024);
}

// Round 2
// 94.209 us; speedup vs baseline: 1.0214x; 1.0214x over previous
//
#include <hip/hip_runtime.h>

typedef unsigned short ushort_t;
typedef unsigned int uint32;

typedef __bf16 bf16x8 __attribute__((ext_vector_type(8)));
typedef float f32x4 __attribute__((ext_vector_type(4)));

#define BAR() asm volatile("s_barrier" ::: "memory")
#define VMCNT(n) asm volatile("s_waitcnt vmcnt(" #n ")" ::: "memory")

// ---------- helpers ----------
__device__ __forceinline__ uint32 f2bf1(float f) {
  uint32 b = __float_as_uint(f);
  return (b + 0x7FFFu + ((b >> 16) & 1u)) >> 16;  // RNE
}
__device__ __forceinline__ uint32 packbf2(float a, float b) {
  return f2bf1(a) | (f2bf1(b) << 16);
}
__device__ __forceinline__ float bflo(uint32 u) { return __uint_as_float(u << 16); }
__device__ __forceinline__ float bfhi(uint32 u) { return __uint_as_float(u & 0xFFFF0000u); }

__device__ __forceinline__ void gload16(const void* g, void* l) {
  __builtin_amdgcn_global_load_lds(
      (const __attribute__((address_space(1))) unsigned int*)g,
      (__attribute__((address_space(3))) unsigned int*)l, 16, 0, 0);
}

// ---------- fp32 -> bf16 elementwise convert ----------
__global__ __launch_bounds__(256) void cvt_f32_bf16(
    const float* __restrict__ in, ushort_t* __restrict__ out, int n4) {
  int i = blockIdx.x * 256 + threadIdx.x;
  if (i < n4) {
    float4 v = ((const float4*)in)[i];
    uint2 r;
    r.x = packbf2(v.x, v.y);
    r.y = packbf2(v.z, v.w);
    ((uint2*)out)[i] = r;
  }
}

// ---------- fp32 [R][Cc] -> bf16 [Cc][R] (transpose + convert) ----------
__global__ __launch_bounds__(256) void transpose_cvt(
    const float* __restrict__ Wsrc, ushort_t* __restrict__ Wt, int R, int Cc) {
  __shared__ float tile[32][33];
  const int tx = threadIdx.x & 31, ty = threadIdx.x >> 5;
  const int c0 = blockIdx.x << 5, r0 = blockIdx.y << 5;
#pragma unroll
  for (int i = 0; i < 4; ++i)
    tile[ty + i * 8][tx] = Wsrc[(size_t)(r0 + ty + i * 8) * Cc + c0 + tx];
  __syncthreads();
#pragma unroll
  for (int i = 0; i < 4; ++i)
    Wt[(size_t)(c0 + ty + i * 8) * R + r0 + tx] = (ushort_t)f2bf1(tile[tx][ty + i * 8]);
}

// ================= 256x256 8-phase bf16 GEMM (T2+T3+T4+T5) =================
// C[M][Nn] (bf16) = A[M][K] * Bt[Nn][K]^T.  M,Nn %256==0, K%64==0, grid %8==0.
// 512 thr = 8 waves (2M x 4N); per-wave 128x64 out; BK=64; LDS 128KiB dbuf.
// LDS map (ushort offsets): buf p: A at p*32768 (+half*8192), B at p*32768+16384.
// Swizzle: 16B chunk slot s holds global chunk s^(row&7) (involution, both sides).

// stage one 128x64 half-tile: 2 x global_load_lds per thread.
__device__ __forceinline__ void stage_half(ushort_t* ldsr, const ushort_t* g,
                                           int ldK, int tid) {
  const int r = tid >> 3, s = tid & 7;
  const int c = ((s ^ (r & 7)) << 3);
  const int wvb = (tid >> 6) << 9;  // wave*512 elem (wave-uniform dest base)
  gload16(g + (size_t)r * ldK + c, ldsr + wvb);
  gload16(g + (size_t)(r + 64) * ldK + c, ldsr + 4096 + wvb);
}

#define READ_A(qm_)                                             \
  {                                                             \
    const int ab = pA + (qm_) * 4096;                           \
    a_k0[0] = *(const bf16x8*)&lds[ab + cK0];                   \
    a_k1[0] = *(const bf16x8*)&lds[ab + cK1];                   \
    a_k0[1] = *(const bf16x8*)&lds[ab + 1024 + cK0];            \
    a_k1[1] = *(const bf16x8*)&lds[ab + 1024 + cK1];            \
    a_k0[2] = *(const bf16x8*)&lds[ab + 2048 + cK0];            \
    a_k1[2] = *(const bf16x8*)&lds[ab + 2048 + cK1];            \
    a_k0[3] = *(const bf16x8*)&lds[ab + 3072 + cK0];            \
    a_k1[3] = *(const bf16x8*)&lds[ab + 3072 + cK1];            \
  }

#define READ_B(bk0, bk1, qn_)                                   \
  {                                                             \
    const int bb = pB + (qn_) * 2048;                           \
    bk0[0] = *(const bf16x8*)&lds[bb + cK0];                    \
    bk1[0] = *(const bf16x8*)&lds[bb + cK1];                    \
    bk0[1] = *(const bf16x8*)&lds[bb + 1024 + cK0];             \
    bk1[1] = *(const bf16x8*)&lds[bb + 1024 + cK1];             \
  }

#define MFMAQ(qm_, qn_, bk0, bk1)                                              \
  {                                                                            \
    _Pragma("unroll") for (int m = 0; m < 4; ++m) {                            \
      acc[(qm_) * 4 + m][(qn_) * 2 + 0] = __builtin_amdgcn_mfma_f32_16x16x32_bf16( \
          a_k0[m], bk0[0], acc[(qm_) * 4 + m][(qn_) * 2 + 0], 0, 0, 0);        \
      acc[(qm_) * 4 + m][(qn_) * 2 + 0] = __builtin_amdgcn_mfma_f32_16x16x32_bf16( \
          a_k1[m], bk1[0], acc[(qm_) * 4 + m][(qn_) * 2 + 0], 0, 0, 0);        \
      acc[(qm_) * 4 + m][(qn_) * 2 + 1] = __builtin_amdgcn_mfma_f32_16x16x32_bf16( \
          a_k0[m], bk0[1], acc[(qm_) * 4 + m][(qn_) * 2 + 1], 0, 0, 0);        \
      acc[(qm_) * 4 + m][(qn_) * 2 + 1] = __builtin_amdgcn_mfma_f32_16x16x32_bf16( \
          a_k1[m], bk1[1], acc[(qm_) * 4 + m][(qn_) * 2 + 1], 0, 0, 0);        \
    }                                                                          \
  }

__global__ __launch_bounds__(512, 2) void gemm8p_bt(
    const ushort_t* __restrict__ A, const ushort_t* __restrict__ Bt,
    ushort_t* __restrict__ C, const int M, const int Nn, const int K) {
  __shared__ ushort_t lds[65536];  // 128 KiB
  const int tid = threadIdx.x;
  const int lane = tid & 63, wave = tid >> 6;
  const int wm = wave >> 2, wn = wave & 3;

  // XCD-aware swizzle (grid %8 == 0)
  const int q8 = gridDim.x >> 3;
  const int wg = (blockIdx.x & 7) * q8 + (blockIdx.x >> 3);
  const int nbn = Nn >> 8;
  const int bm = (wg / nbn) << 8;
  const int bn = (wg % nbn) << 8;
  const int nt = K >> 6;

  const int l15 = lane & 15, l16 = lane >> 4, l7 = l15 & 7;
  const int cK0 = ((l16 ^ l7) << 3);
  const int cK1 = (((4 + l16) ^ l7) << 3);

  f32x4 acc[8][4] = {};
  bf16x8 a_k0[4], a_k1[4], b0_k0[2], b0_k1[2], b1_k0[2], b1_k1[2];

  // ---- prologue: tile0 full + B(tile1); allow tile1-B in flight ----
  stage_half(&lds[0], A + (size_t)bm * K, K, tid);
  stage_half(&lds[8192], A + (size_t)(bm + 128) * K, K, tid);
  stage_half(&lds[16384], Bt + (size_t)bn * K, K, tid);
  stage_half(&lds[16384 + 8192], Bt + (size_t)(bn + 128) * K, K, tid);
  stage_half(&lds[32768 + 16384], Bt + (size_t)bn * K + 64, K, tid);
  stage_half(&lds[32768 + 16384 + 8192], Bt + (size_t)(bn + 128) * K + 64, K, tid);
  VMCNT(4);
  BAR();

  for (int U = 0; U < nt; ++U) {
    const int p = U & 1;
    const int pA = p * 32768 + wm * 8192 + l15 * 64;
    const int pB = p * 32768 + 16384 + (wn >> 1) * 8192 + ((wn & 1) * 64 + l15) * 64;
    const bool sA = (U + 1) < nt;
    const bool sB = (U + 2) < nt;

    // ---- phase 1: A[qm0], B[qn0]; stage A0(U+1) ----
    READ_A(0);
    READ_B(b0_k0, b0_k1, 0);
    if (sA) stage_half(&lds[(p ^ 1) * 32768], A + (size_t)bm * K + (U + 1) * 64, K, tid);
    BAR();
    __builtin_amdgcn_s_setprio(1);
    MFMAQ(0, 0, b0_k0, b0_k1);
    __builtin_amdgcn_s_setprio(0);
    BAR();

    // ---- phase 2: B[qn1]; stage A1(U+1) ----
    READ_B(b1_k0, b1_k1, 1);
    if (sA) stage_half(&lds[(p ^ 1) * 32768 + 8192], A + (size_t)(bm + 128) * K + (U + 1) * 64, K, tid);
    BAR();
    __builtin_amdgcn_s_setprio(1);
    MFMAQ(0, 1, b1_k0, b1_k1);
    __builtin_amdgcn_s_setprio(0);
    BAR();

    // ---- phase 3: A[qm1]; stage B0(U+2) ----
    READ_A(1);
    if (sB) stage_half(&lds[p * 32768 + 16384], Bt + (size_t)bn * K + (U + 2) * 64, K, tid);
    BAR();
    __builtin_amdgcn_s_setprio(1);
    MFMAQ(1, 1, b1_k0, b1_k1);
    __builtin_amdgcn_s_setprio(0);
    BAR();

    // ---- phase 4: no reads; stage B1(U+2); counted wait ----
    if (sB) stage_half(&lds[p * 32768 + 16384 + 8192], Bt + (size_t)(bn + 128) * K + (U + 2) * 64, K, tid);
    BAR();
    __builtin_amdgcn_s_setprio(1);
    MFMAQ(1, 0, b0_k0, b0_k1);
    __builtin_amdgcn_s_setprio(0);
    if (sB) {
      VMCNT(4);   // keep B(U+2)'s 4 loads in flight across the boundary
    } else {
      VMCNT(0);   // epilogue drain
    }
    BAR();
  }

  // ---- epilogue: C/D layout col=lane&15, row=(lane>>4)*4+reg ----
  const int crow0 = bm + wm * 128 + (l16 << 2);
  const int ccol0 = bn + wn * 64 + l15;
#pragma unroll
  for (int m = 0; m < 8; ++m)
#pragma unroll
    for (int n = 0; n < 4; ++n)
#pragma unroll
      for (int j = 0; j < 4; ++j)
        C[(size_t)(crow0 + m * 16 + j) * Nn + ccol0 + n * 16] =
            (ushort_t)f2bf1(acc[m][n][j]);
}

// ---------- m97-style 128x128 GEMM (kept for proj): C fp32 + bias ----------
template <bool OUT_BF16>
__global__ __launch_bounds__(256) void gemm_bt(
    const ushort_t* __restrict__ A, const ushort_t* __restrict__ Bt,
    void* __restrict__ Cout, const float* __restrict__ bias,
    const int M, const int Nn, const int K) {
  __shared__ ushort_t lA[128 * 32];
  __shared__ ushort_t lB[128 * 32];
  const int tid = threadIdx.x;
  const int lane = tid & 63, wave = tid >> 6;
  const int wm = wave >> 1, wn = wave & 1;
  const int bm = blockIdx.y << 7, bn = blockIdx.x << 7;

  f32x4 acc[4][4] = {};

  const int srow = tid >> 2, schk = tid & 3;
  const ushort_t* gA = A + (size_t)(bm + srow) * K + schk * 8;
  const ushort_t* gB = Bt + (size_t)(bn + srow) * K + schk * 8;
  ushort_t* lA0 = lA + wave * 512;
  ushort_t* lB0 = lB + wave * 512;

  const int la_off = ((wm << 6) + (lane & 15)) * 32 + ((lane >> 4) << 3);
  const int lb_off = ((wn << 6) + (lane & 15)) * 32 + ((lane >> 4) << 3);

  for (int k0 = 0; k0 < K; k0 += 32) {
    gload16(gA + k0, lA0);
    gload16(gA + k0 + 64 * K, lA0 + 2048);
    gload16(gB + k0, lB0);
    gload16(gB + k0 + 64 * K, lB0 + 2048);
    __syncthreads();
    bf16x8 a[4], b[4];
#pragma unroll
    for (int m = 0; m < 4; ++m) a[m] = *(const bf16x8*)&lA[la_off + m * 512];
#pragma unroll
    for (int n = 0; n < 4; ++n) b[n] = *(const bf16x8*)&lB[lb_off + n * 512];
#pragma unroll
    for (int m = 0; m < 4; ++m)
#pragma unroll
      for (int n = 0; n < 4; ++n)
        acc[m][n] = __builtin_amdgcn_mfma_f32_16x16x32_bf16(a[m], b[n], acc[m][n], 0, 0, 0);
    __syncthreads();
  }

  const int r0 = bm + (wm << 6) + ((lane >> 4) << 2);
  const int c0 = bn + (wn << 6) + (lane & 15);
#pragma unroll
  for (int m = 0; m < 4; ++m)
#pragma unroll
    for (int n = 0; n < 4; ++n)
#pragma unroll
      for (int j = 0; j < 4; ++j) {
        const int row = r0 + m * 16 + j;
        const int col = c0 + n * 16;
        if (OUT_BF16)
          ((ushort_t*)Cout)[(size_t)row * Nn + col] = (ushort_t)f2bf1(acc[m][n][j]);
        else
          ((float*)Cout)[(size_t)row * Nn + col] = acc[m][n][j] + bias[col];
      }
}

// ---------- banded attention (unchanged) ----------
__global__ __launch_bounds__(256) void attn_band(
    const ushort_t* __restrict__ qkv, ushort_t* __restrict__ aout) {
  __shared__ float Ks[80 * 68];
  __shared__ float Vs[80 * 68];
  const int tid = threadIdx.x;
  const int i0 = blockIdx.x << 6;
  const int h = blockIdx.y;
  const int b = blockIdx.z;
  const size_t rowbase = (size_t)b * 2048;

  for (int idx = tid; idx < 1280; idx += 256) {
    const int t = idx >> 4, c = idx & 15;
    const int j = i0 - 8 + t;
    float k0 = 0.f, k1 = 0.f, k2 = 0.f, k3 = 0.f;
    float v0 = 0.f, v1 = 0.f, v2 = 0.f, v3 = 0.f;
    if ((unsigned)j < 2048u) {
      const ushort_t* p = qkv + (rowbase + j) * 3072 + (h << 6) + (c << 2);
      uint2 rk = *(const uint2*)(p + 1024);
      uint2 rv = *(const uint2*)(p + 2048);
      k0 = bflo(rk.x); k1 = bfhi(rk.x); k2 = bflo(rk.y); k3 = bfhi(rk.y);
      v0 = bflo(rv.x); v1 = bfhi(rv.x); v2 = bflo(rv.y); v3 = bfhi(rv.y);
    }
    *(float4*)&Ks[t * 68 + (c << 2)] = make_float4(k0, k1, k2, k3);
    *(float4*)&Vs[t * 68 + (c << 2)] = make_float4(v0, v1, v2, v3);
  }
  __syncthreads();

  const int lane = tid & 63, wv = tid >> 6;
  const int qs = lane >> 2, dg = lane & 3;
  const int qi = (wv << 4) + qs;
  const int i = i0 + qi;

  const ushort_t* qp = qkv + (rowbase + i) * 3072 + (h << 6) + (dg << 4);
  float q[16];
  {
    uint4 u0 = *(const uint4*)qp;
    uint4 u1 = *(const uint4*)(qp + 8);
    q[0] = bflo(u0.x); q[1] = bfhi(u0.x); q[2] = bflo(u0.y); q[3] = bfhi(u0.y);
    q[4] = bflo(u0.z); q[5] = bfhi(u0.z); q[6] = bflo(u0.w); q[7] = bfhi(u0.w);
    q[8] = bflo(u1.x); q[9] = bfhi(u1.x); q[10] = bflo(u1.y); q[11] = bfhi(u1.y);
    q[12] = bflo(u1.z); q[13] = bfhi(u1.z); q[14] = bflo(u1.w); q[15] = bfhi(u1.w);
  }

  float s[17];
#pragma unroll
  for (int jo = 0; jo < 17; ++jo) {
    const float* kr = &Ks[(qi + jo) * 68 + (dg << 4)];
    float d = 0.f;
#pragma unroll
    for (int c = 0; c < 4; ++c) {
      float4 kv = *(const float4*)(kr + (c << 2));
      d += q[c * 4 + 0] * kv.x + q[c * 4 + 1] * kv.y +
           q[c * 4 + 2] * kv.z + q[c * 4 + 3] * kv.w;
    }
    d += __shfl_xor(d, 1);
    d += __shfl_xor(d, 2);
    const int jg = i - 8 + jo;
    s[jo] = ((unsigned)jg < 2048u) ? d * 0.125f : -1e30f;
  }
  float m = s[0];
#pragma unroll
  for (int jo = 1; jo < 17; ++jo) m = fmaxf(m, s[jo]);
  float sum = 0.f;
#pragma unroll
  for (int jo = 0; jo < 17; ++jo) {
    s[jo] = __expf(s[jo] - m);
    sum += s[jo];
  }
  const float inv = 1.f / sum;

  float o[16];
#pragma unroll
  for (int dd = 0; dd < 16; ++dd) o[dd] = 0.f;
#pragma unroll
  for (int jo = 0; jo < 17; ++jo) {
    const float* vr = &Vs[(qi + jo) * 68 + (dg << 4)];
    const float w = s[jo];
#pragma unroll
    for (int c = 0; c < 4; ++c) {
      float4 vv = *(const float4*)(vr + (c << 2));
      o[c * 4 + 0] += w * vv.x; o[c * 4 + 1] += w * vv.y;
      o[c * 4 + 2] += w * vv.z; o[c * 4 + 3] += w * vv.w;
    }
  }

  ushort_t* op = aout + (rowbase + i) * 1024 + (h << 6) + (dg << 4);
  uint4 w0, w1;
  w0.x = packbf2(o[0] * inv, o[1] * inv);
  w0.y = packbf2(o[2] * inv, o[3] * inv);
  w0.z = packbf2(o[4] * inv, o[5] * inv);
  w0.w = packbf2(o[6] * inv, o[7] * inv);
  w1.x = packbf2(o[8] * inv, o[9] * inv);
  w1.y = packbf2(o[10] * inv, o[11] * inv);
  w1.z = packbf2(o[12] * inv, o[13] * inv);
  w1.w = packbf2(o[14] * inv, o[15] * inv);
  *(uint4*)op = w0;
  *(uint4*)(op + 8) = w1;
}

// ---------- launch ----------
extern "C" void kernel_launch(void* const* d_in, const int* in_sizes, int n_in,
                              void* d_out, int out_size, void* d_ws, size_t ws_size,
                              hipStream_t stream) {
  const float* x = (const float*)d_in[0];
  const float* Wqkv = (const float*)d_in[1];
  const float* Wproj = (const float*)d_in[2];
  const float* bproj = (const float*)d_in[3];
  float* out = (float*)d_out;

  char* ws = (char*)d_ws;
  ushort_t* xb    = (ushort_t*)(ws);
  ushort_t* wqkvT = (ushort_t*)(ws + (8u << 20));
  ushort_t* wprT  = (ushort_t*)(ws + (14u << 20));
  ushort_t* qkv   = (ushort_t*)(ws + (16u << 20));
  ushort_t* aoutb = (ushort_t*)(ws + (40u << 20));

  cvt_f32_bf16<<<4096, 256, 0, stream>>>(x, xb, 1048576);
  transpose_cvt<<<dim3(96, 32), 256, 0, stream>>>(Wqkv, wqkvT, 1024, 3072);
  transpose_cvt<<<dim3(32, 32), 256, 0, stream>>>(Wproj, wprT, 1024, 1024);
  gemm8p_bt<<<192, 512, 0, stream>>>(xb, wqkvT, qkv, 4096, 3072, 1024);
  attn_band<<<dim3(32, 16, 2), 256, 0, stream>>>(qkv, aoutb);
  gemm_bt<false><<<dim3(8, 32), 256, 0, stream>>>(aoutb, wprT, out, bproj, 4096, 1024, 1024);
}

// Round 3
// 92.608 us; speedup vs baseline: 1.0391x; 1.0173x over previous
//
#include <hip/hip_runtime.h>

typedef unsigned short ushort_t;
typedef unsigned int uint32;

typedef __bf16 bf16x8 __attribute__((ext_vector_type(8)));
typedef float f32x4 __attribute__((ext_vector_type(4)));

#define BAR() __builtin_amdgcn_s_barrier()
#define LGKM0() asm volatile("s_waitcnt lgkmcnt(0)")
#define VMCNT(n) asm volatile("s_waitcnt vmcnt(" #n ")")

// ---------- helpers ----------
__device__ __forceinline__ uint32 f2bf1(float f) {
  uint32 b = __float_as_uint(f);
  return (b + 0x7FFFu + ((b >> 16) & 1u)) >> 16;  // RNE
}
__device__ __forceinline__ uint32 packbf2(float a, float b) {
  return f2bf1(a) | (f2bf1(b) << 16);
}
__device__ __forceinline__ float bflo(uint32 u) { return __uint_as_float(u << 16); }
__device__ __forceinline__ float bfhi(uint32 u) { return __uint_as_float(u & 0xFFFF0000u); }

__device__ __forceinline__ void gload16(const void* g, void* l) {
  __builtin_amdgcn_global_load_lds(
      (const __attribute__((address_space(1))) unsigned int*)g,
      (__attribute__((address_space(3))) unsigned int*)l, 16, 0, 0);
}

// ---------- fp32 -> bf16 elementwise convert ----------
__global__ __launch_bounds__(256) void cvt_f32_bf16(
    const float* __restrict__ in, ushort_t* __restrict__ out, int n4) {
  int i = blockIdx.x * 256 + threadIdx.x;
  if (i < n4) {
    float4 v = ((const float4*)in)[i];
    uint2 r;
    r.x = packbf2(v.x, v.y);
    r.y = packbf2(v.z, v.w);
    ((uint2*)out)[i] = r;
  }
}

// ---------- both weights: fp32 [R][Cc] -> bf16 [Cc][R] in one launch ----------
__global__ __launch_bounds__(256) void transpose_cvt2(
    const float* __restrict__ Wqkv, ushort_t* __restrict__ wqkvT,
    const float* __restrict__ Wproj, ushort_t* __restrict__ wprT) {
  __shared__ float tile[32][33];
  const int tx = threadIdx.x & 31, ty = threadIdx.x >> 5;
  const int bx = blockIdx.x;
  const float* src;
  ushort_t* dst;
  int Cc, c0;
  if (bx < 96) { src = Wqkv; dst = wqkvT; Cc = 3072; c0 = bx << 5; }
  else         { src = Wproj; dst = wprT; Cc = 1024; c0 = (bx - 96) << 5; }
  const int r0 = blockIdx.y << 5;  // R = 1024
#pragma unroll
  for (int i = 0; i < 4; ++i)
    tile[ty + i * 8][tx] = src[(size_t)(r0 + ty + i * 8) * Cc + c0 + tx];
  __syncthreads();
#pragma unroll
  for (int i = 0; i < 4; ++i)
    dst[(size_t)(c0 + ty + i * 8) * 1024 + r0 + tx] = (ushort_t)f2bf1(tile[tx][ty + i * 8]);
}

// ================= 256x256 8-phase bf16 GEMM (T2+T3+T4+T5) =================
// C[M][Nn] (bf16) = A[M][K] * Bt[Nn][K]^T.  M,Nn %256==0, K%64==0, grid %8==0.
// 512 thr = 8 waves (2M x 4N); per-wave 128x64 out; BK=64; LDS 128KiB dbuf.
// LDS map (ushort offsets): buf p: A at p*32768 (+half*8192), B at p*32768+16384.
// Swizzle: 16B chunk slot s holds global chunk s^(row&7) (involution, both sides).

__device__ __forceinline__ void stage_half(ushort_t* ldsr, const ushort_t* g,
                                           int ldK, int tid) {
  const int r = tid >> 3, s = tid & 7;
  const int c = ((s ^ (r & 7)) << 3);
  const int wvb = (tid >> 6) << 9;  // wave*512 elem (wave-uniform dest base)
  gload16(g + (size_t)r * ldK + c, ldsr + wvb);
  gload16(g + (size_t)(r + 64) * ldK + c, ldsr + 4096 + wvb);
}

#define READ_A(qm_)                                             \
  {                                                             \
    const int ab = pA + (qm_) * 4096;                           \
    a_k0[0] = *(const bf16x8*)&lds[ab + cK0];                   \
    a_k1[0] = *(const bf16x8*)&lds[ab + cK1];                   \
    a_k0[1] = *(const bf16x8*)&lds[ab + 1024 + cK0];            \
    a_k1[1] = *(const bf16x8*)&lds[ab + 1024 + cK1];            \
    a_k0[2] = *(const bf16x8*)&lds[ab + 2048 + cK0];            \
    a_k1[2] = *(const bf16x8*)&lds[ab + 2048 + cK1];            \
    a_k0[3] = *(const bf16x8*)&lds[ab + 3072 + cK0];            \
    a_k1[3] = *(const bf16x8*)&lds[ab + 3072 + cK1];            \
  }

#define READ_B(bk0, bk1, qn_)                                   \
  {                                                             \
    const int bb = pB + (qn_) * 2048;                           \
    bk0[0] = *(const bf16x8*)&lds[bb + cK0];                    \
    bk1[0] = *(const bf16x8*)&lds[bb + cK1];                    \
    bk0[1] = *(const bf16x8*)&lds[bb + 1024 + cK0];             \
    bk1[1] = *(const bf16x8*)&lds[bb + 1024 + cK1];             \
  }

#define MFMAQ(qm_, qn_, bk0, bk1)                                              \
  {                                                                            \
    _Pragma("unroll") for (int m = 0; m < 4; ++m) {                            \
      acc[(qm_) * 4 + m][(qn_) * 2 + 0] = __builtin_amdgcn_mfma_f32_16x16x32_bf16( \
          a_k0[m], bk0[0], acc[(qm_) * 4 + m][(qn_) * 2 + 0], 0, 0, 0);        \
      acc[(qm_) * 4 + m][(qn_) * 2 + 0] = __builtin_amdgcn_mfma_f32_16x16x32_bf16( \
          a_k1[m], bk1[0], acc[(qm_) * 4 + m][(qn_) * 2 + 0], 0, 0, 0);        \
      acc[(qm_) * 4 + m][(qn_) * 2 + 1] = __builtin_amdgcn_mfma_f32_16x16x32_bf16( \
          a_k0[m], bk0[1], acc[(qm_) * 4 + m][(qn_) * 2 + 1], 0, 0, 0);        \
      acc[(qm_) * 4 + m][(qn_) * 2 + 1] = __builtin_amdgcn_mfma_f32_16x16x32_bf16( \
          a_k1[m], bk1[1], acc[(qm_) * 4 + m][(qn_) * 2 + 1], 0, 0, 0);        \
    }                                                                          \
  }

__global__ __launch_bounds__(512, 2) void gemm8p_bt(
    const ushort_t* __restrict__ A, const ushort_t* __restrict__ Bt,
    ushort_t* __restrict__ C, const int M, const int Nn, const int K) {
  __shared__ ushort_t lds[65536];  // 128 KiB
  const int tid = threadIdx.x;
  const int lane = tid & 63, wave = tid >> 6;
  const int wm = wave >> 2, wn = wave & 3;

  // XCD-aware swizzle (grid %8 == 0)
  const int q8 = gridDim.x >> 3;
  const int wg = (blockIdx.x & 7) * q8 + (blockIdx.x >> 3);
  const int nbn = Nn >> 8;
  const int bm = (wg / nbn) << 8;
  const int bn = (wg % nbn) << 8;
  const int nt = K >> 6;

  const int l15 = lane & 15, l16 = lane >> 4, l7 = l15 & 7;
  const int cK0 = ((l16 ^ l7) << 3);
  const int cK1 = (((4 + l16) ^ l7) << 3);

  f32x4 acc[8][4] = {};
  bf16x8 a_k0[4], a_k1[4], b0_k0[2], b0_k1[2], b1_k0[2], b1_k1[2];

  // ---- prologue: tile0 full + B(tile1); keep tile1-B in flight ----
  stage_half(&lds[0], A + (size_t)bm * K, K, tid);
  stage_half(&lds[8192], A + (size_t)(bm + 128) * K, K, tid);
  stage_half(&lds[16384], Bt + (size_t)bn * K, K, tid);
  stage_half(&lds[16384 + 8192], Bt + (size_t)(bn + 128) * K, K, tid);
  stage_half(&lds[32768 + 16384], Bt + (size_t)bn * K + 64, K, tid);
  stage_half(&lds[32768 + 16384 + 8192], Bt + (size_t)(bn + 128) * K + 64, K, tid);
  VMCNT(4);
  BAR();

  for (int U = 0; U < nt; ++U) {
    const int p = U & 1;
    const int pA = p * 32768 + wm * 8192 + l15 * 64;
    const int pB = p * 32768 + 16384 + (wn >> 1) * 8192 + ((wn & 1) * 64 + l15) * 64;
    const bool sA = (U + 1) < nt;
    const bool sB = (U + 2) < nt;

    // ---- phase 1: reads A[qm0],B[qn0]; stage A0(U+1) ----
    READ_A(0);
    READ_B(b0_k0, b0_k1, 0);
    if (sA) stage_half(&lds[(p ^ 1) * 32768], A + (size_t)bm * K + (U + 1) * 64, K, tid);
    BAR();
    LGKM0();
    __builtin_amdgcn_s_setprio(1);
    MFMAQ(0, 0, b0_k0, b0_k1);
    __builtin_amdgcn_s_setprio(0);
    BAR();

    // ---- phase 2: reads B[qn1]; stage A1(U+1) ----
    READ_B(b1_k0, b1_k1, 1);
    if (sA) stage_half(&lds[(p ^ 1) * 32768 + 8192], A + (size_t)(bm + 128) * K + (U + 1) * 64, K, tid);
    BAR();
    LGKM0();
    __builtin_amdgcn_s_setprio(1);
    MFMAQ(0, 1, b1_k0, b1_k1);
    __builtin_amdgcn_s_setprio(0);
    BAR();

    // ---- phase 3: reads A[qm1]; stage B0(U+2) ----
    READ_A(1);
    if (sB) stage_half(&lds[p * 32768 + 16384], Bt + (size_t)bn * K + (U + 2) * 64, K, tid);
    BAR();
    LGKM0();
    __builtin_amdgcn_s_setprio(1);
    MFMAQ(1, 1, b1_k0, b1_k1);
    __builtin_amdgcn_s_setprio(0);
    BAR();

    // ---- phase 4: no reads; stage B1(U+2); counted wait once per K-tile ----
    if (sB) stage_half(&lds[p * 32768 + 16384 + 8192], Bt + (size_t)(bn + 128) * K + (U + 2) * 64, K, tid);
    BAR();
    __builtin_amdgcn_s_setprio(1);
    MFMAQ(1, 0, b0_k0, b0_k1);
    __builtin_amdgcn_s_setprio(0);
    if (sB) {
      VMCNT(4);   // keep B(U+2)'s 4 loads in flight across the tile boundary
    } else {
      VMCNT(0);   // tail drain
    }
    BAR();
  }

  // ---- epilogue: C/D layout col=lane&15, row=(lane>>4)*4+reg ----
  const int crow0 = bm + wm * 128 + (l16 << 2);
  const int ccol0 = bn + wn * 64 + l15;
#pragma unroll
  for (int m = 0; m < 8; ++m)
#pragma unroll
    for (int n = 0; n < 4; ++n)
#pragma unroll
      for (int j = 0; j < 4; ++j)
        C[(size_t)(crow0 + m * 16 + j) * Nn + ccol0 + n * 16] =
            (ushort_t)f2bf1(acc[m][n][j]);
}

// ---------- m97-style 128x128 GEMM (proj): C fp32 + bias ----------
template <bool OUT_BF16>
__global__ __launch_bounds__(256) void gemm_bt(
    const ushort_t* __restrict__ A, const ushort_t* __restrict__ Bt,
    void* __restrict__ Cout, const float* __restrict__ bias,
    const int M, const int Nn, const int K) {
  __shared__ ushort_t lA[128 * 32];
  __shared__ ushort_t lB[128 * 32];
  const int tid = threadIdx.x;
  const int lane = tid & 63, wave = tid >> 6;
  const int wm = wave >> 1, wn = wave & 1;
  const int bm = blockIdx.y << 7, bn = blockIdx.x << 7;

  f32x4 acc[4][4] = {};

  const int srow = tid >> 2, schk = tid & 3;
  const ushort_t* gA = A + (size_t)(bm + srow) * K + schk * 8;
  const ushort_t* gB = Bt + (size_t)(bn + srow) * K + schk * 8;
  ushort_t* lA0 = lA + wave * 512;
  ushort_t* lB0 = lB + wave * 512;

  const int la_off = ((wm << 6) + (lane & 15)) * 32 + ((lane >> 4) << 3);
  const int lb_off = ((wn << 6) + (lane & 15)) * 32 + ((lane >> 4) << 3);

  for (int k0 = 0; k0 < K; k0 += 32) {
    gload16(gA + k0, lA0);
    gload16(gA + k0 + 64 * K, lA0 + 2048);
    gload16(gB + k0, lB0);
    gload16(gB + k0 + 64 * K, lB0 + 2048);
    __syncthreads();
    bf16x8 a[4], b[4];
#pragma unroll
    for (int m = 0; m < 4; ++m) a[m] = *(const bf16x8*)&lA[la_off + m * 512];
#pragma unroll
    for (int n = 0; n < 4; ++n) b[n] = *(const bf16x8*)&lB[lb_off + n * 512];
#pragma unroll
    for (int m = 0; m < 4; ++m)
#pragma unroll
      for (int n = 0; n < 4; ++n)
        acc[m][n] = __builtin_amdgcn_mfma_f32_16x16x32_bf16(a[m], b[n], acc[m][n], 0, 0, 0);
    __syncthreads();
  }

  const int r0 = bm + (wm << 6) + ((lane >> 4) << 2);
  const int c0 = bn + (wn << 6) + (lane & 15);
#pragma unroll
  for (int m = 0; m < 4; ++m)
#pragma unroll
    for (int n = 0; n < 4; ++n)
#pragma unroll
      for (int j = 0; j < 4; ++j) {
        const int row = r0 + m * 16 + j;
        const int col = c0 + n * 16;
        if (OUT_BF16)
          ((ushort_t*)Cout)[(size_t)row * Nn + col] = (ushort_t)f2bf1(acc[m][n][j]);
        else
          ((float*)Cout)[(size_t)row * Nn + col] = acc[m][n][j] + bias[col];
      }
}

// ---------- banded attention ----------
__global__ __launch_bounds__(256) void attn_band(
    const ushort_t* __restrict__ qkv, ushort_t* __restrict__ aout) {
  __shared__ float Ks[80 * 68];
  __shared__ float Vs[80 * 68];
  const int tid = threadIdx.x;
  const int i0 = blockIdx.x << 6;
  const int h = blockIdx.y;
  const int b = blockIdx.z;
  const size_t rowbase = (size_t)b * 2048;

  for (int idx = tid; idx < 1280; idx += 256) {
    const int t = idx >> 4, c = idx & 15;
    const int j = i0 - 8 + t;
    float k0 = 0.f, k1 = 0.f, k2 = 0.f, k3 = 0.f;
    float v0 = 0.f, v1 = 0.f, v2 = 0.f, v3 = 0.f;
    if ((unsigned)j < 2048u) {
      const ushort_t* p = qkv + (rowbase + j) * 3072 + (h << 6) + (c << 2);
      uint2 rk = *(const uint2*)(p + 1024);
      uint2 rv = *(const uint2*)(p + 2048);
      k0 = bflo(rk.x); k1 = bfhi(rk.x); k2 = bflo(rk.y); k3 = bfhi(rk.y);
      v0 = bflo(rv.x); v1 = bfhi(rv.x); v2 = bflo(rv.y); v3 = bfhi(rv.y);
    }
    *(float4*)&Ks[t * 68 + (c << 2)] = make_float4(k0, k1, k2, k3);
    *(float4*)&Vs[t * 68 + (c << 2)] = make_float4(v0, v1, v2, v3);
  }
  __syncthreads();

  const int lane = tid & 63, wv = tid >> 6;
  const int qs = lane >> 2, dg = lane & 3;
  const int qi = (wv << 4) + qs;
  const int i = i0 + qi;

  const ushort_t* qp = qkv + (rowbase + i) * 3072 + (h << 6) + (dg << 4);
  float q[16];
  {
    uint4 u0 = *(const uint4*)qp;
    uint4 u1 = *(const uint4*)(qp + 8);
    q[0] = bflo(u0.x); q[1] = bfhi(u0.x); q[2] = bflo(u0.y); q[3] = bfhi(u0.y);
    q[4] = bflo(u0.z); q[5] = bfhi(u0.z); q[6] = bflo(u0.w); q[7] = bfhi(u0.w);
    q[8] = bflo(u1.x); q[9] = bfhi(u1.x); q[10] = bflo(u1.y); q[11] = bfhi(u1.y);
    q[12] = bflo(u1.z); q[13] = bfhi(u1.z); q[14] = bflo(u1.w); q[15] = bfhi(u1.w);
  }

  float s[17];
#pragma unroll
  for (int jo = 0; jo < 17; ++jo) {
    const float* kr = &Ks[(qi + jo) * 68 + (dg << 4)];
    float d = 0.f;
#pragma unroll
    for (int c = 0; c < 4; ++c) {
      float4 kv = *(const float4*)(kr + (c << 2));
      d += q[c * 4 + 0] * kv.x + q[c * 4 + 1] * kv.y +
           q[c * 4 + 2] * kv.z + q[c * 4 + 3] * kv.w;
    }
    d += __shfl_xor(d, 1);
    d += __shfl_xor(d, 2);
    const int jg = i - 8 + jo;
    s[jo] = ((unsigned)jg < 2048u) ? d * 0.125f : -1e30f;
  }
  float m = s[0];
#pragma unroll
  for (int jo = 1; jo < 17; ++jo) m = fmaxf(m, s[jo]);
  float sum = 0.f;
#pragma unroll
  for (int jo = 0; jo < 17; ++jo) {
    s[jo] = __expf(s[jo] - m);
    sum += s[jo];
  }
  const float inv = 1.f / sum;

  float o[16];
#pragma unroll
  for (int dd = 0; dd < 16; ++dd) o[dd] = 0.f;
#pragma unroll
  for (int jo = 0; jo < 17; ++jo) {
    const float* vr = &Vs[(qi + jo) * 68 + (dg << 4)];
    const float w = s[jo];
#pragma unroll
    for (int c = 0; c < 4; ++c) {
      float4 vv = *(const float4*)(vr + (c << 2));
      o[c * 4 + 0] += w * vv.x; o[c * 4 + 1] += w * vv.y;
      o[c * 4 + 2] += w * vv.z; o[c * 4 + 3] += w * vv.w;
    }
  }

  ushort_t* op = aout + (rowbase + i) * 1024 + (h << 6) + (dg << 4);
  uint4 w0, w1;
  w0.x = packbf2(o[0] * inv, o[1] * inv);
  w0.y = packbf2(o[2] * inv, o[3] * inv);
  w0.z = packbf2(o[4] * inv, o[5] * inv);
  w0.w = packbf2(o[6] * inv, o[7] * inv);
  w1.x = packbf2(o[8] * inv, o[9] * inv);
  w1.y = packbf2(o[10] * inv, o[11] * inv);
  w1.z = packbf2(o[12] * inv, o[13] * inv);
  w1.w = packbf2(o[14] * inv, o[15] * inv);
  *(uint4*)op = w0;
  *(uint4*)(op + 8) = w1;
}

// ---------- launch ----------
extern "C" void kernel_launch(void* const* d_in, const int* in_sizes, int n_in,
                              void* d_out, int out_size, void* d_ws, size_t ws_size,
                              hipStream_t stream) {
  const float* x = (const float*)d_in[0];
  const float* Wqkv = (const float*)d_in[1];
  const float* Wproj = (const float*)d_in[2];
  const float* bproj = (const float*)d_in[3];
  float* out = (float*)d_out;

  char* ws = (char*)d_ws;
  ushort_t* xb    = (ushort_t*)(ws);
  ushort_t* wqkvT = (ushort_t*)(ws + (8u << 20));
  ushort_t* wprT  = (ushort_t*)(ws + (14u << 20));
  ushort_t* qkv   = (ushort_t*)(ws + (16u << 20));
  ushort_t* aoutb = (ushort_t*)(ws + (40u << 20));

  cvt_f32_bf16<<<4096, 256, 0, stream>>>(x, xb, 1048576);
  transpose_cvt2<<<dim3(128, 32), 256, 0, stream>>>(Wqkv, wqkvT, Wproj, wprT);
  gemm8p_bt<<<192, 512, 0, stream>>>(xb, wqkvT, qkv, 4096, 3072, 1024);
  attn_band<<<dim3(32, 16, 2), 256, 0, stream>>>(qkv, aoutb);
  gemm_bt<false><<<dim3(8, 32), 256, 0, stream>>>(aoutb, wprT, out, bproj, 4096, 1024, 1024);
}